// Round 6
// baseline (801.548 us; speedup 1.0000x reference)
//
#include <hip/hip_runtime.h>
#include <stdint.h>

#define FP8_MAX 448.0f

typedef float f32x4 __attribute__((ext_vector_type(4)));
typedef int i32x8 __attribute__((ext_vector_type(8)));
typedef int i32x4 __attribute__((ext_vector_type(4)));

// ---------- fp8 pack helper (HW RNE conversion, clamp to ±448 like the reference's clip) ----------
__device__ __forceinline__ unsigned int pack4_fp8(float4 v, float s) {
  float a = fminf(fmaxf(v.x * s, -FP8_MAX), FP8_MAX);
  float b = fminf(fmaxf(v.y * s, -FP8_MAX), FP8_MAX);
  float c = fminf(fmaxf(v.z * s, -FP8_MAX), FP8_MAX);
  float d = fminf(fmaxf(v.w * s, -FP8_MAX), FP8_MAX);
  unsigned int r = (unsigned int)__builtin_amdgcn_cvt_pk_fp8_f32(a, b, 0, false);
  r = (unsigned int)__builtin_amdgcn_cvt_pk_fp8_f32(c, d, (int)r, true);
  return r;
}

// ---------- async global->LDS 16B ----------
__device__ __forceinline__ void load16_to_lds(const void* g, void* l) {
  auto gp = (const __attribute__((address_space(1))) void*)(uintptr_t)g;
  auto lp = (__attribute__((address_space(3))) void*)(unsigned int)(uintptr_t)l;
  __builtin_amdgcn_global_load_lds(gp, lp, 16, 0, 0);
}

__device__ __forceinline__ float amax4(float4 v) {
  return fmaxf(fmaxf(fabsf(v.x), fabsf(v.y)), fmaxf(fabsf(v.z), fabsf(v.w)));
}

// 256-thread (4-wave) block max-reduce; result valid in all threads.
__device__ __forceinline__ float block_reduce_max256(float m, float* wred) {
#pragma unroll
  for (int off = 32; off > 0; off >>= 1)
    m = fmaxf(m, __shfl_down(m, off, 64));
  int lane = threadIdx.x & 63;
  int wv = threadIdx.x >> 6;
  if (lane == 0) wred[wv] = m;
  __syncthreads();
  return fmaxf(fmaxf(wred[0], wred[1]), fmaxf(wred[2], wred[3]));
}

// ---------- per-tensor amax partials (NO atomics, NO memset needed: every slot written) ----------
// blocks 0..2047 -> x partials, 2048..2559 -> w partials.
__global__ void amax2_kernel(const float* __restrict__ x, int n4x,
                             const float* __restrict__ w, int n4w,
                             float* __restrict__ partials) {
  __shared__ float wred[4];
  const float4* p4;
  int n4, base, nblk;
  if (blockIdx.x < 2048) {
    p4 = (const float4*)x; n4 = n4x; base = blockIdx.x; nblk = 2048;
  } else {
    p4 = (const float4*)w; n4 = n4w; base = blockIdx.x - 2048; nblk = 512;
  }
  int stride = nblk * blockDim.x;
  int i = base * blockDim.x + threadIdx.x;
  float m = 0.0f;
  for (; i + 3 * stride < n4; i += 4 * stride) {
    float4 v0 = p4[i];
    float4 v1 = p4[i + stride];
    float4 v2 = p4[i + 2 * stride];
    float4 v3 = p4[i + 3 * stride];
    m = fmaxf(m, fmaxf(fmaxf(amax4(v0), amax4(v1)), fmaxf(amax4(v2), amax4(v3))));
  }
  for (; i < n4; i += stride) m = fmaxf(m, amax4(p4[i]));
  m = block_reduce_max256(m, wred);
  if (threadIdx.x == 0) partials[blockIdx.x] = m;
}

// ---------- fused quantize: x -> xq (blocks 0..2047) and w -> wqT (blocks 2048..6143) ----------
// Each block re-reduces the (L2-resident, 10 KB) partial array for its tensor's amax.
// Block 0 additionally publishes both amaxes to hdrf[0..1] for the GEMM epilogue
// (visible to the GEMM via the dispatch boundary).
__global__ void quant_fused_kernel(const float* __restrict__ x, unsigned int* __restrict__ xq,
                                   int n16x,
                                   const float* __restrict__ w, unsigned char* __restrict__ wqT,
                                   int K, int N,
                                   const float* __restrict__ partials,
                                   float* __restrict__ hdrf) {
  __shared__ float wred[4];
  __shared__ unsigned int tileT[64][17];  // only used by w-blocks
  const bool isX = blockIdx.x < 2048;
  const float* pp = isX ? partials : partials + 2048;
  const int np = isX ? 2048 : 512;
  float pm = 0.0f;
  for (int i = threadIdx.x; i < np; i += 256) pm = fmaxf(pm, pp[i]);
  float am = block_reduce_max256(pm, wred);
  float s = FP8_MAX / fmaxf(am, 1e-12f);

  if (blockIdx.x == 0) {  // publish both amaxes (block 0 is an x-block)
    __syncthreads();      // protect wred reuse
    float pw = 0.0f;
    for (int i = threadIdx.x; i < 512; i += 256) pw = fmaxf(pw, partials[2048 + i]);
    float aw = block_reduce_max256(pw, wred);
    if (threadIdx.x == 0) { hdrf[0] = am; hdrf[1] = aw; }
  }

  if (isX) {
    const float4* x4 = (const float4*)x;
    uint4* o4 = (uint4*)xq;
    int stride = 2048 * blockDim.x;
    for (int i = blockIdx.x * blockDim.x + threadIdx.x; i < n16x; i += stride) {
      float4 a = x4[4 * i + 0];
      float4 b = x4[4 * i + 1];
      float4 c = x4[4 * i + 2];
      float4 d = x4[4 * i + 3];
      o4[i] = make_uint4(pack4_fp8(a, s), pack4_fp8(b, s), pack4_fp8(c, s), pack4_fp8(d, s));
    }
  } else {
    int bx = blockIdx.x - 2048;
    int tn0 = (bx & 63) << 6;
    int tk0 = (bx >> 6) << 6;
    int t = threadIdx.x;

    int rn = (t & 15) << 2;   // n within tile; adjacent lanes -> adjacent 16B => coalesced
    int rk = (t >> 4) << 2;   // k within tile
    unsigned int wrow[4];
#pragma unroll
    for (int j = 0; j < 4; ++j) {
      float4 v = *(const float4*)(w + (size_t)(tk0 + rk + j) * N + tn0 + rn);
      wrow[j] = pack4_fp8(v, s);  // bytes = cols n..n+3 of row k+j
    }
#pragma unroll
    for (int i = 0; i < 4; ++i) {
      unsigned int colw = ((wrow[0] >> (8 * i)) & 0xffu)
                        | (((wrow[1] >> (8 * i)) & 0xffu) << 8)
                        | (((wrow[2] >> (8 * i)) & 0xffu) << 16)
                        | (((wrow[3] >> (8 * i)) & 0xffu) << 24);
      tileT[rn + i][rk >> 2] = colw;  // bytes = rows k..k+3 of col n+i
    }
    __syncthreads();

    int n = t >> 2;
    int kc = (t & 3) << 2;  // word index within row
    uint4 v = make_uint4(tileT[n][kc], tileT[n][kc + 1], tileT[n][kc + 2], tileT[n][kc + 3]);
    *(uint4*)(wqT + (size_t)(tn0 + n) * K + tk0 + (kc << 2)) = v;
  }
}

// ---------- helpers for the GEMM ----------
__device__ __forceinline__ i32x8 read_frag(const unsigned char* p, int off0) {
  i32x4 lo = *(const i32x4*)(p + off0);
  i32x4 hi = *(const i32x4*)(p + (off0 ^ 16));
  return __builtin_shufflevector(lo, hi, 0, 1, 2, 3, 4, 5, 6, 7);
}

#define MFMA1(a, b, c) \
  __builtin_amdgcn_mfma_scale_f32_16x16x128_f8f6f4(a, b, c, 0, 0, 0, 0x7f7f7f7f, 0, 0x7f7f7f7f)

// one C-quadrant: 4 M-frags (AF_) x 2 N-frags. NO setprio: its intrinsic side effects
// fence the scheduler and quarantine the MFMA cluster -- this design WANTS the compiler
// to interleave ds_reads with MFMAs (the round-3 phase structure serialized the LDS pipe
// (~96K cy/block) against the MFMA pipe (~70K cy/block): 166K ~= the 187K cy measured).
#define MFMA_Q(AF_, B0_, B1_, M0_, N0_)                                   \
  do {                                                                    \
    acc[M0_ + 0][N0_ + 0] = MFMA1(AF_[0], B0_, acc[M0_ + 0][N0_ + 0]);    \
    acc[M0_ + 0][N0_ + 1] = MFMA1(AF_[0], B1_, acc[M0_ + 0][N0_ + 1]);    \
    acc[M0_ + 1][N0_ + 0] = MFMA1(AF_[1], B0_, acc[M0_ + 1][N0_ + 0]);    \
    acc[M0_ + 1][N0_ + 1] = MFMA1(AF_[1], B1_, acc[M0_ + 1][N0_ + 1]);    \
    acc[M0_ + 2][N0_ + 0] = MFMA1(AF_[2], B0_, acc[M0_ + 2][N0_ + 0]);    \
    acc[M0_ + 2][N0_ + 1] = MFMA1(AF_[2], B1_, acc[M0_ + 2][N0_ + 1]);    \
    acc[M0_ + 3][N0_ + 0] = MFMA1(AF_[3], B0_, acc[M0_ + 3][N0_ + 0]);    \
    acc[M0_ + 3][N0_ + 1] = MFMA1(AF_[3], B1_, acc[M0_ + 3][N0_ + 1]);    \
  } while (0)

#define BAR() __builtin_amdgcn_s_barrier()
#define SCHED0() __builtin_amdgcn_sched_barrier(0)
#define LGKM0() asm volatile("s_waitcnt lgkmcnt(0)" ::: "memory")
#define VMCNT0() asm volatile("s_waitcnt vmcnt(0)" ::: "memory")

// ---------- fp8 GEMM, 256x256 tile, 8-wave, 2-barrier/K-tile, early-staged dbuf ----------
// MX-scaled K=128 MFMA (identity e8m0 scales). LDS: 2 dbuf x (A 32KB + B 32KB) = 128 KB
// (1 block/CU, LDS-limited -- register use up to 256/wave is free).
// Per K-tile t: stage ALL of tile t+1 into the other buffer FIRST (8 global_load_lds,
// pinned early by one sched_barrier), then the full 24 ds_read_b128 + 32 MFMA interior
// with NO fences -- the compiler's automatic counted lgkmcnt interleaves the two pipes
// (LDS ~96K cy/block and MFMA ~70K cy/block overlap instead of serializing).
// End of tile: lgkmcnt(0) (WAR safety for next staging) + vmcnt(0) (t+1 resident; its
// loads were issued a full ~3000-cy window earlier, so the drain is ~free) + barrier.
__global__ __launch_bounds__(512, 2) void gemm_fp8_kernel(
    const unsigned char* __restrict__ Aq,   // [M,K] fp8
    const unsigned char* __restrict__ Bq,   // [N,K] fp8 (w transposed)
    const float* __restrict__ hdrf,         // [0]=amax_x, [1]=amax_w
    float* __restrict__ out, int M, int N, int K) {
  __shared__ __align__(16) unsigned char smem[131072];  // A: [0,64K), B: [64K,128K)

  const int t = threadIdx.x;
  const int wave = t >> 6;
  const int lane = t & 63;
  const int row16 = lane & 15;
  const int quad = lane >> 4;
  const int wr = wave >> 2;           // 0..1  (M-half of the 256 rows)
  const int wc = wave & 3;            // 0..3  (N-quarter)
  const int m0 = blockIdx.y << 8;
  const int n0 = blockIdx.x << 8;

  // ---- staging geometry: per call a wave writes 8 rows x 128B (lane-linear in LDS).
  // Global source chunk pre-swizzled: physical chunk p of row r holds logical p^(r&7).
  const int sRow = (wave << 3) + (lane >> 3);                 // 0..63
  const int sCol = (((lane & 7) ^ (lane >> 3)) << 4);         // inverse-swizzled source
  const unsigned char* agBase = Aq + (size_t)(m0 + sRow) * K + sCol;
  const unsigned char* bgBase = Bq + (size_t)(n0 + sRow) * K + sCol;
  const int ldsStageOff = (wave << 10) + (lane << 4);

  auto stageT = [&](int u) {  // full K-tile u (A 32KB + B 32KB) -> buffer u&1; 8 loads/lane
    const int buf = (u & 1) << 15;
#pragma unroll
    for (int h = 0; h < 2; ++h)
#pragma unroll
      for (int r = 0; r < 2; ++r) {
        load16_to_lds(agBase + (size_t)((h << 7) + (r << 6)) * K + ((size_t)u << 7),
                      smem + buf + (h << 14) + (r << 13) + ldsStageOff);
        load16_to_lds(bgBase + (size_t)((h << 7) + (r << 6)) * K + ((size_t)u << 7),
                      smem + 65536 + buf + (h << 14) + (r << 13) + ldsStageOff);
      }
  };

  // ---- fragment addressing: lane holds row (lane&15), k-bytes quad*32..+31 =
  // logical chunks {2q,2q+1}; physical = logical ^ (row&7).
  const int off0 = (((quad << 1) ^ (row16 & 7)) << 4);        // second 16B at off0^16
  const int aRow = (wr << 7) + row16;                         // + mi*16
  const int bRow = (wc << 6) + row16;                         // + ni*16

  f32x4 acc[8][4] = {};

  const int NT = K >> 7;  // 128B K-tiles (=32)

  // ---- prologue: stage tile0, drain, sync (one-time cost)
  stageT(0);
  VMCNT0();
  BAR();

  for (int tt = 0; tt < NT; ++tt) {
    const int buf = (tt & 1) << 15;
    const unsigned char* Ab = smem + buf;
    const unsigned char* Bb = smem + 65536 + buf;
    const bool more = (tt + 1 < NT);

    if (more) stageT(tt + 1);   // issue next tile's 8 loads FIRST (max prefetch distance)
    SCHED0();                   // pin staging issue before the compute interior

    i32x8 afA[4], afB[4], bf[4];
    afA[0] = read_frag(Ab + ((aRow + 0) << 7), off0);
    afA[1] = read_frag(Ab + ((aRow + 16) << 7), off0);
    afA[2] = read_frag(Ab + ((aRow + 32) << 7), off0);
    afA[3] = read_frag(Ab + ((aRow + 48) << 7), off0);
    bf[0] = read_frag(Bb + ((bRow + 0) << 7), off0);
    bf[1] = read_frag(Bb + ((bRow + 16) << 7), off0);
    MFMA_Q(afA, bf[0], bf[1], 0, 0);
    bf[2] = read_frag(Bb + ((bRow + 32) << 7), off0);
    bf[3] = read_frag(Bb + ((bRow + 48) << 7), off0);
    MFMA_Q(afA, bf[2], bf[3], 0, 2);
    afB[0] = read_frag(Ab + ((aRow + 64) << 7), off0);
    afB[1] = read_frag(Ab + ((aRow + 80) << 7), off0);
    afB[2] = read_frag(Ab + ((aRow + 96) << 7), off0);
    afB[3] = read_frag(Ab + ((aRow + 112) << 7), off0);
    MFMA_Q(afB, bf[0], bf[1], 4, 0);
    MFMA_Q(afB, bf[2], bf[3], 4, 2);

    LGKM0();                    // all my reads retired (WAR safety for next staging)
    if (more) VMCNT0();         // t+1 resident; loads issued a full window ago
    BAR();
  }

  // ---- epilogue: dequant scale = (amax_x/448)*(amax_w/448)
  const float ax = fmaxf(hdrf[0], 1e-12f);
  const float aw = fmaxf(hdrf[1], 1e-12f);
  const float sc = (ax / FP8_MAX) * (aw / FP8_MAX);
#pragma unroll
  for (int mi = 0; mi < 8; ++mi) {
#pragma unroll
    for (int ni = 0; ni < 4; ++ni) {
      const int gc = n0 + (wc << 6) + ni * 16 + row16;
#pragma unroll
      for (int r = 0; r < 4; ++r) {
        const int gr = m0 + (wr << 7) + mi * 16 + quad * 4 + r;
        out[(size_t)gr * N + gc] = acc[mi][ni][r] * sc;  // C/D: col=lane&15, row=quad*4+reg
      }
    }
  }
}

extern "C" void kernel_launch(void* const* d_in, const int* in_sizes, int n_in,
                              void* d_out, int out_size, void* d_ws, size_t ws_size,
                              hipStream_t stream) {
  const float* x = (const float*)d_in[0];       // [M,K] fp32 (flattened [8,2048,4096])
  const float* w = (const float*)d_in[1];       // [K,N] fp32
  float* out = (float*)d_out;

  const int K = 4096;
  const int N = 4096;
  const int M = in_sizes[0] / K;                // 16384

  // workspace layout: [0,10240) partials (2048 x + 512 w, every slot written -> no
  // memset needed on poisoned ws), [12288,12296) hdr floats, [16384,...) xq, wqT.
  float* partials = (float*)d_ws;
  float* hdrf = (float*)((char*)d_ws + 12288);
  unsigned char* xq = (unsigned char*)d_ws + 16384;
  unsigned char* wqT = xq + (size_t)M * K;

  amax2_kernel<<<2560, 256, 0, stream>>>(x, (int)((size_t)M * K / 4), w,
                                         (int)((size_t)K * N / 4), partials);

  quant_fused_kernel<<<2048 + 4096, 256, 0, stream>>>(
      x, (unsigned int*)xq, (int)((size_t)M * K / 16), w, wqT, K, N, partials, hdrf);

  gemm_fp8_kernel<<<dim3(N / 256, M / 256), 512, 0, stream>>>(xq, wqT, hdrf, out, M, N, K);
}